// Round 8
// baseline (558.692 us; speedup 1.0000x reference)
//
#include <hip/hip_runtime.h>
#include <hip/hip_bf16.h>

#define D_DIM 2048
#define F_DIM 1024
#define E_NUM 16
#define T_TOK 2048

typedef float f32x4 __attribute__((ext_vector_type(4)));
typedef short short8 __attribute__((ext_vector_type(8)));
typedef unsigned uint2v __attribute__((ext_vector_type(2)));

__device__ inline unsigned pk2bf(float a, float b) {
    __hip_bfloat162 h2 = __float22bfloat162_rn(make_float2(a, b));
    union { __hip_bfloat162 h; unsigned u; } c; c.h = h2; return c.u;
}

// ---------------- routing: 1 wave per token ----------------
__global__ __launch_bounds__(64) void k_route(const float* __restrict__ x,
                                              const float* __restrict__ wg,
                                              const float* __restrict__ bias,
                                              int* __restrict__ topk_idx,
                                              float* __restrict__ topk_w,
                                              int* __restrict__ counts) {
    int t = blockIdx.x;
    int l = threadIdx.x;
    int e = l & 15, c = l >> 4;
    const float* xr = x + (size_t)t * D_DIM + c * (D_DIM / 4);
    const float* wr = wg + (size_t)(c * (D_DIM / 4)) * E_NUM + e;
    float acc = 0.f;
#pragma unroll 4
    for (int d = 0; d < D_DIM / 4; ++d) acc += xr[d] * wr[(size_t)d * E_NUM];
    acc += __shfl_xor(acc, 16);
    acc += __shfl_xor(acc, 32);
    float m = acc;
#pragma unroll
    for (int s = 1; s < 16; s <<= 1) m = fmaxf(m, __shfl_xor(m, s));
    float p = __expf(acc - m);
    float sum = p;
#pragma unroll
    for (int s = 1; s < 16; s <<= 1) sum += __shfl_xor(sum, s);
    p = p / sum + bias[e];
    float v1 = p; int i1 = e;
#pragma unroll
    for (int s = 1; s < 16; s <<= 1) {
        float ov = __shfl_xor(v1, s); int oi = __shfl_xor(i1, s);
        if (ov > v1 || (ov == v1 && oi < i1)) { v1 = ov; i1 = oi; }
    }
    float v2 = (e == i1) ? -1e30f : p; int i2 = e;
#pragma unroll
    for (int s = 1; s < 16; s <<= 1) {
        float ov = __shfl_xor(v2, s); int oi = __shfl_xor(i2, s);
        if (ov > v2 || (ov == v2 && oi < i2)) { v2 = ov; i2 = oi; }
    }
    if (l == 0) {
        float s2 = v1 + v2 + 1e-20f;
        topk_idx[2 * t] = i1; topk_idx[2 * t + 1] = i2;
        topk_w[2 * t] = v1 / s2; topk_w[2 * t + 1] = v2 / s2;
        atomicAdd(&counts[i1], 1);
        atomicAdd(&counts[i2], 1);
    }
}

__global__ void k_offsets(const int* __restrict__ counts, int* __restrict__ offsets,
                          int* __restrict__ cursors) {
    if (threadIdx.x == 0) {
        int run = 0;
        for (int e = 0; e < E_NUM; ++e) { offsets[e] = run; cursors[e] = run; run += counts[e]; }
        offsets[E_NUM] = run;
    }
}

__global__ void k_scatter(const int* __restrict__ topk_idx, const float* __restrict__ topk_w,
                          int* __restrict__ cursors, int* __restrict__ token_ids,
                          float* __restrict__ slot_w) {
    int i = blockIdx.x * blockDim.x + threadIdx.x;
    if (i >= T_TOK * 2) return;
    int e = topk_idx[i];
    int slot = atomicAdd(&cursors[e], 1);
    token_ids[slot] = i >> 1;
    slot_w[slot] = topk_w[i];
}

// ================= gate+up grouped GEMM — wave-autonomous =================
// Block 64 slots x 64 F-cols = 4 independent waves, each 32x32. NO __syncthreads
// in the K-loop: each wave stages its private 32-col B slice (K-major bf16,
// [32 cols][40] shorts, R5-verified XOR swizzle) and reads A-fragments directly
// from global (k-contiguous per lane). Waves free-run -> continuous MLP.
__global__ __launch_bounds__(256, 3) void k_gateup(const float* __restrict__ x,
                                                   const float* __restrict__ wg_all,
                                                   const float* __restrict__ wu_all,
                                                   const int* __restrict__ offsets,
                                                   const int* __restrict__ token_ids,
                                                   __hip_bfloat16* __restrict__ hbuf) {
    int e = blockIdx.z;
    int off = offsets[e];
    int n_e = offsets[e + 1] - off;
    int m0 = blockIdx.y * 64;
    if (m0 >= n_e) return;
    int n0 = blockIdx.x * 64;
    const float* wg = wg_all + (size_t)e * (D_DIM * F_DIM);
    const float* wu = wu_all + (size_t)e * (D_DIM * F_DIM);

    __shared__ unsigned short Bs[4][2][32 * 40];   // [wave][mat][col][40]

    int tid = threadIdx.x;
    int wid = tid >> 6, lane = tid & 63;
    int q = lane >> 4, nl = lane & 15;
    int wr = wid >> 1, wc = wid & 1;
    int colbase = n0 + wc * 32;

    // A rows for this lane's fragments (row = nl within each 16-row strip)
    int r0 = m0 + wr * 32 + nl;        // ms=0
    int r1 = r0 + 16;                  // ms=1
    const float* xr0 = x + (size_t)token_ids[off + (r0 < n_e ? r0 : 0)] * D_DIM;
    const float* xr1 = x + (size_t)token_ids[off + (r1 < n_e ? r1 : 0)] * D_DIM;

    // B staging map: lane -> colgroup cg (4 cols), k-quad kb4
    int cg = lane & 7;
    int kb4 = (lane >> 3) * 4;
    const float* pg0 = wg + (size_t)kb4 * F_DIM + colbase + cg * 4;
    const float* pu0 = wu + (size_t)kb4 * F_DIM + colbase + cg * 4;
    unsigned short* BG = &Bs[wid][0][0];
    unsigned short* BU = &Bs[wid][1][0];

    f32x4 accG[2][2], accU[2][2];
#pragma unroll
    for (int ms = 0; ms < 2; ++ms)
#pragma unroll
        for (int ns = 0; ns < 2; ++ns) {
            accG[ms][ns] = (f32x4){0.f, 0.f, 0.f, 0.f};
            accU[ms][ns] = (f32x4){0.f, 0.f, 0.f, 0.f};
        }

    f32x4 g0, g1, g2, g3, u0, u1, u2, u3;     // staged W rows kb4..kb4+3 (4 cols)
    auto loadW = [&](int k0) {
        const float* pg = pg0 + (size_t)k0 * F_DIM;
        const float* pu = pu0 + (size_t)k0 * F_DIM;
        g0 = *(const f32x4*)pg; g1 = *(const f32x4*)(pg + F_DIM);
        g2 = *(const f32x4*)(pg + 2 * F_DIM); g3 = *(const f32x4*)(pg + 3 * F_DIM);
        u0 = *(const f32x4*)pu; u1 = *(const f32x4*)(pu + F_DIM);
        u2 = *(const f32x4*)(pu + 2 * F_DIM); u3 = *(const f32x4*)(pu + 3 * F_DIM);
    };
    auto writeW = [&]() {
#pragma unroll
        for (int j = 0; j < 4; ++j) {
            int col = cg * 4 + j;
            int kk = kb4 ^ (((col >> 3) & 3) << 3);
            uint2v vg, vu;
            vg[0] = pk2bf(g0[j], g1[j]); vg[1] = pk2bf(g2[j], g3[j]);
            vu[0] = pk2bf(u0[j], u1[j]); vu[1] = pk2bf(u2[j], u3[j]);
            *(uint2v*)&BG[col * 40 + kk] = vg;
            *(uint2v*)&BU[col * 40 + kk] = vu;
        }
    };
    auto compute = [&](int k0) {
        // A fragments direct from global (fp32 -> bf16)
        f32x4 a00 = *(const f32x4*)(xr0 + k0 + q * 8);
        f32x4 a01 = *(const f32x4*)(xr0 + k0 + q * 8 + 4);
        f32x4 a10 = *(const f32x4*)(xr1 + k0 + q * 8);
        f32x4 a11 = *(const f32x4*)(xr1 + k0 + q * 8 + 4);
        union { short8 v; unsigned u[4]; } af0, af1;
        af0.u[0] = pk2bf(a00.x, a00.y); af0.u[1] = pk2bf(a00.z, a00.w);
        af0.u[2] = pk2bf(a01.x, a01.y); af0.u[3] = pk2bf(a01.z, a01.w);
        af1.u[0] = pk2bf(a10.x, a10.y); af1.u[1] = pk2bf(a10.z, a10.w);
        af1.u[2] = pk2bf(a11.x, a11.y); af1.u[3] = pk2bf(a11.z, a11.w);
#pragma unroll
        for (int ns = 0; ns < 2; ++ns) {
            int col = ns * 16 + nl;
            int cb = col * 40 + 8 * (q ^ ((col >> 3) & 3));
            short8 bg = *(const short8*)&BG[cb];
            short8 bu = *(const short8*)&BU[cb];
            accG[0][ns] = __builtin_amdgcn_mfma_f32_16x16x32_bf16(af0.v, bg, accG[0][ns], 0, 0, 0);
            accG[1][ns] = __builtin_amdgcn_mfma_f32_16x16x32_bf16(af1.v, bg, accG[1][ns], 0, 0, 0);
            accU[0][ns] = __builtin_amdgcn_mfma_f32_16x16x32_bf16(af0.v, bu, accU[0][ns], 0, 0, 0);
            accU[1][ns] = __builtin_amdgcn_mfma_f32_16x16x32_bf16(af1.v, bu, accU[1][ns], 0, 0, 0);
        }
    };

    loadW(0);
    writeW();
    for (int t = 0; t < D_DIM / 32; ++t) {
        if (t < D_DIM / 32 - 1) loadW((t + 1) * 32);
        compute(t * 32);                      // in-order DS: reads before next writes
        if (t < D_DIM / 32 - 1) writeW();
    }

    // epilogue: silu(g)*u -> bf16 ; D layout: col=lane&15, row=(lane>>4)*4+j
#pragma unroll
    for (int ms = 0; ms < 2; ++ms)
#pragma unroll
        for (int j = 0; j < 4; ++j) {
            int g2r = m0 + wr * 32 + ms * 16 + q * 4 + j;
            if (g2r < n_e) {
                size_t hbase = (size_t)(off + g2r) * F_DIM;
#pragma unroll
                for (int ns = 0; ns < 2; ++ns) {
                    float g = accG[ms][ns][j];
                    float u = accU[ms][ns][j];
                    float hv = (g / (1.f + __expf(-g))) * u;
                    hbuf[hbase + colbase + ns * 16 + nl] = __float2bfloat16(hv);
                }
            }
        }
}

// ================= down grouped GEMM — wave-autonomous + atomic combine =================
__global__ __launch_bounds__(256, 3) void k_down(const __hip_bfloat16* __restrict__ hbuf,
                                                 const float* __restrict__ wd_all,
                                                 const int* __restrict__ offsets,
                                                 const int* __restrict__ token_ids,
                                                 const float* __restrict__ slot_w,
                                                 float* __restrict__ y) {
    int e = blockIdx.z;
    int off = offsets[e];
    int n_e = offsets[e + 1] - off;
    int m0 = blockIdx.y * 64;
    if (m0 >= n_e) return;
    int n0 = blockIdx.x * 64;
    const float* wd = wd_all + (size_t)e * (F_DIM * D_DIM);

    __shared__ unsigned short Bs[4][32 * 40];

    int tid = threadIdx.x;
    int wid = tid >> 6, lane = tid & 63;
    int q = lane >> 4, nl = lane & 15;
    int wr = wid >> 1, wc = wid & 1;
    int colbase = n0 + wc * 32;

    int r0 = m0 + wr * 32 + nl;
    int r1 = r0 + 16;
    const unsigned short* h0 = (const unsigned short*)hbuf + (size_t)(off + (r0 < n_e ? r0 : 0)) * F_DIM;
    const unsigned short* h1 = (const unsigned short*)hbuf + (size_t)(off + (r1 < n_e ? r1 : 0)) * F_DIM;

    int cg = lane & 7;
    int kb4 = (lane >> 3) * 4;
    const float* pd0 = wd + (size_t)kb4 * D_DIM + colbase + cg * 4;
    unsigned short* BD = &Bs[wid][0];

    f32x4 acc[2][2];
#pragma unroll
    for (int ms = 0; ms < 2; ++ms)
#pragma unroll
        for (int ns = 0; ns < 2; ++ns) acc[ms][ns] = (f32x4){0.f, 0.f, 0.f, 0.f};

    f32x4 d0, d1, d2, d3;
    auto loadW = [&](int k0) {
        const float* pd = pd0 + (size_t)k0 * D_DIM;
        d0 = *(const f32x4*)pd; d1 = *(const f32x4*)(pd + D_DIM);
        d2 = *(const f32x4*)(pd + 2 * D_DIM); d3 = *(const f32x4*)(pd + 3 * D_DIM);
    };
    auto writeW = [&]() {
#pragma unroll
        for (int j = 0; j < 4; ++j) {
            int col = cg * 4 + j;
            int kk = kb4 ^ (((col >> 3) & 3) << 3);
            uint2v vd;
            vd[0] = pk2bf(d0[j], d1[j]); vd[1] = pk2bf(d2[j], d3[j]);
            *(uint2v*)&BD[col * 40 + kk] = vd;
        }
    };
    auto compute = [&](int k0) {
        short8 af0 = *(const short8*)(h0 + k0 + q * 8);
        short8 af1 = *(const short8*)(h1 + k0 + q * 8);
#pragma unroll
        for (int ns = 0; ns < 2; ++ns) {
            int col = ns * 16 + nl;
            short8 bd = *(const short8*)&BD[col * 40 + 8 * (q ^ ((col >> 3) & 3))];
            acc[0][ns] = __builtin_amdgcn_mfma_f32_16x16x32_bf16(af0, bd, acc[0][ns], 0, 0, 0);
            acc[1][ns] = __builtin_amdgcn_mfma_f32_16x16x32_bf16(af1, bd, acc[1][ns], 0, 0, 0);
        }
    };

    loadW(0);
    writeW();
    for (int t = 0; t < F_DIM / 32; ++t) {
        if (t < F_DIM / 32 - 1) loadW((t + 1) * 32);
        compute(t * 32);
        if (t < F_DIM / 32 - 1) writeW();
    }

#pragma unroll
    for (int ms = 0; ms < 2; ++ms)
#pragma unroll
        for (int j = 0; j < 4; ++j) {
            int g2r = m0 + wr * 32 + ms * 16 + q * 4 + j;
            if (g2r < n_e) {
                float w2 = slot_w[off + g2r];
                int t = token_ids[off + g2r];
#pragma unroll
                for (int ns = 0; ns < 2; ++ns)
                    atomicAdd(&y[(size_t)t * D_DIM + colbase + ns * 16 + nl], acc[ms][ns][j] * w2);
            }
        }
}

extern "C" void kernel_launch(void* const* d_in, const int* in_sizes, int n_in,
                              void* d_out, int out_size, void* d_ws, size_t ws_size,
                              hipStream_t stream) {
    const float* x      = (const float*)d_in[0];
    const float* w_gate = (const float*)d_in[1];
    const float* w_g    = (const float*)d_in[2];
    const float* w_u    = (const float*)d_in[3];
    const float* w_d    = (const float*)d_in[4];
    const float* bias   = (const float*)d_in[5];
    float* y = (float*)d_out;

    char* ws = (char*)d_ws;
    int*   counts    = (int*)(ws + 0);
    int*   offsets   = (int*)(ws + 64);
    int*   cursors   = (int*)(ws + 192);
    int*   topk_idx  = (int*)(ws + 256);
    float* topk_w    = (float*)(ws + 256 + 16384);
    int*   token_ids = (int*)(ws + 256 + 32768);
    float* slot_w    = (float*)(ws + 256 + 49152);
    __hip_bfloat16* hbuf = (__hip_bfloat16*)(ws + 66048);   // 4096*1024 bf16

    hipMemsetAsync(ws, 0, 256, stream);
    hipMemsetAsync(d_out, 0, (size_t)out_size * sizeof(float), stream);

    k_route<<<T_TOK, 64, 0, stream>>>(x, w_gate, bias, topk_idx, topk_w, counts);
    k_offsets<<<1, 64, 0, stream>>>(counts, offsets, cursors);
    k_scatter<<<(T_TOK * 2 + 255) / 256, 256, 0, stream>>>(topk_idx, topk_w, cursors, token_ids, slot_w);
    k_gateup<<<dim3(F_DIM / 64, 32, E_NUM), 256, 0, stream>>>(x, w_g, w_u, offsets, token_ids, hbuf);
    k_down<<<dim3(D_DIM / 64, 32, E_NUM), 256, 0, stream>>>(hbuf, w_d, offsets, token_ids, slot_w, y);
}

// Round 9
// 429.120 us; speedup vs baseline: 1.3019x; 1.3019x over previous
//
#include <hip/hip_runtime.h>
#include <hip/hip_bf16.h>

#define D_DIM 2048
#define F_DIM 1024
#define E_NUM 16
#define T_TOK 2048

typedef float f32x4 __attribute__((ext_vector_type(4)));
typedef short short8 __attribute__((ext_vector_type(8)));

__device__ inline unsigned pk2bf(float a, float b) {
    __hip_bfloat162 h2 = __float22bfloat162_rn(make_float2(a, b));
    union { __hip_bfloat162 h; unsigned u; } c; c.h = h2; return c.u;
}

// ---------------- routing: 1 wave per token ----------------
__global__ __launch_bounds__(64) void k_route(const float* __restrict__ x,
                                              const float* __restrict__ wg,
                                              const float* __restrict__ bias,
                                              int* __restrict__ topk_idx,
                                              float* __restrict__ topk_w,
                                              int* __restrict__ counts) {
    int t = blockIdx.x;
    int l = threadIdx.x;
    int e = l & 15, c = l >> 4;
    const float* xr = x + (size_t)t * D_DIM + c * (D_DIM / 4);
    const float* wr = wg + (size_t)(c * (D_DIM / 4)) * E_NUM + e;
    float acc = 0.f;
#pragma unroll 4
    for (int d = 0; d < D_DIM / 4; ++d) acc += xr[d] * wr[(size_t)d * E_NUM];
    acc += __shfl_xor(acc, 16);
    acc += __shfl_xor(acc, 32);
    float m = acc;
#pragma unroll
    for (int s = 1; s < 16; s <<= 1) m = fmaxf(m, __shfl_xor(m, s));
    float p = __expf(acc - m);
    float sum = p;
#pragma unroll
    for (int s = 1; s < 16; s <<= 1) sum += __shfl_xor(sum, s);
    p = p / sum + bias[e];
    float v1 = p; int i1 = e;
#pragma unroll
    for (int s = 1; s < 16; s <<= 1) {
        float ov = __shfl_xor(v1, s); int oi = __shfl_xor(i1, s);
        if (ov > v1 || (ov == v1 && oi < i1)) { v1 = ov; i1 = oi; }
    }
    float v2 = (e == i1) ? -1e30f : p; int i2 = e;
#pragma unroll
    for (int s = 1; s < 16; s <<= 1) {
        float ov = __shfl_xor(v2, s); int oi = __shfl_xor(i2, s);
        if (ov > v2 || (ov == v2 && oi < i2)) { v2 = ov; i2 = oi; }
    }
    if (l == 0) {
        float s2 = v1 + v2 + 1e-20f;
        topk_idx[2 * t] = i1; topk_idx[2 * t + 1] = i2;
        topk_w[2 * t] = v1 / s2; topk_w[2 * t + 1] = v2 / s2;
        atomicAdd(&counts[i1], 1);
        atomicAdd(&counts[i2], 1);
    }
}

__global__ void k_offsets(const int* __restrict__ counts, int* __restrict__ offsets,
                          int* __restrict__ cursors) {
    if (threadIdx.x == 0) {
        int run = 0;
        for (int e = 0; e < E_NUM; ++e) { offsets[e] = run; cursors[e] = run; run += counts[e]; }
        offsets[E_NUM] = run;
    }
}

__global__ void k_scatter(const int* __restrict__ topk_idx, const float* __restrict__ topk_w,
                          int* __restrict__ cursors, int* __restrict__ token_ids,
                          float* __restrict__ slot_w) {
    int i = blockIdx.x * blockDim.x + threadIdx.x;
    if (i >= T_TOK * 2) return;
    int e = topk_idx[i];
    int slot = atomicAdd(&cursors[e], 1);
    token_ids[slot] = i >> 1;
    slot_w[slot] = topk_w[i];
}

// ================= gate+up grouped GEMM =================
// tile 128(slots) x 32(F), BK=32, 4 waves each owning a 32x32 sub-tile,
// double-buffered, compiler-scheduled loop (R5 structure). N halved vs R5 ->
// 2x grid (4 blocks/CU) at UNCHANGED W traffic (W slice read by 2 m-blocks).
// A LDS: [128 rows][32 k] bf16, stride 40 shorts (R5-identical).
// B LDS: K-major [32 cols][32 k] bf16, stride 40, R5-verified XOR swizzle:
//   element (col,k) at col*40 + (k ^ (((col>>3)&3)<<3)); read b128 at 8*(q^((col>>3)&3)).
// B staging: waves 0-1 stage Wg, waves 2-3 stage Wu (wave-uniform split).
__global__ __launch_bounds__(256, 4) void k_gateup(const float* __restrict__ x,
                                                   const float* __restrict__ wg_all,
                                                   const float* __restrict__ wu_all,
                                                   const int* __restrict__ offsets,
                                                   const int* __restrict__ token_ids,
                                                   __hip_bfloat16* __restrict__ hbuf) {
    int e = blockIdx.z;
    int off = offsets[e];
    int n_e = offsets[e + 1] - off;
    int m0 = blockIdx.y * 128;
    if (m0 >= n_e) return;
    int n0 = blockIdx.x * 32;
    const float* wg = wg_all + (size_t)e * (D_DIM * F_DIM);
    const float* wu = wu_all + (size_t)e * (D_DIM * F_DIM);

    __shared__ unsigned short As[2][128 * 40];
    __shared__ unsigned short Bs[2][2][32 * 40];

    int tid = threadIdx.x;
    int wid = tid >> 6, lane = tid & 63;
    int q = lane >> 4, nl = lane & 15;

    // A staging: 2 threads/row, 16 fp32 each (R5-identical)
    int arow = tid >> 1, acg = (tid & 1) * 16;
    int ag = m0 + arow;
    bool avalid = ag < n_e;
    const float* xrow = x + (size_t)token_ids[off + (avalid ? ag : 0)] * D_DIM;
    // B staging: mat = tid>>7 (0:Wg waves0-1, 1:Wu waves2-3);
    // within 128 threads: k-pair rows {bkr,bkr+1}, cols bcol..bcol+3
    int bmat = tid >> 7;
    int t7 = tid & 127;
    int bkr = (t7 >> 3) * 2;
    int bcol = (t7 & 7) * 4;
    const float* wmat = bmat ? wu : wg;

    f32x4 ra[4], rw[2];
    f32x4 accG[2][2], accU[2][2];
#pragma unroll
    for (int ms = 0; ms < 2; ++ms)
#pragma unroll
        for (int ns = 0; ns < 2; ++ns) {
            accG[ms][ns] = (f32x4){0.f, 0.f, 0.f, 0.f};
            accU[ms][ns] = (f32x4){0.f, 0.f, 0.f, 0.f};
        }

    auto loadG = [&](int k0) {
#pragma unroll
        for (int j = 0; j < 4; ++j)
            ra[j] = avalid ? *(const f32x4*)(xrow + k0 + acg + 4 * j) : (f32x4){0.f, 0.f, 0.f, 0.f};
        size_t o0 = (size_t)(k0 + bkr) * F_DIM + n0 + bcol;
        rw[0] = *(const f32x4*)(wmat + o0);
        rw[1] = *(const f32x4*)(wmat + o0 + F_DIM);
    };
    auto writeL = [&](int b) {
        unsigned short* a = &As[b][arow * 40 + acg];
        union { short8 v; unsigned u[4]; } w0, w1;
        w0.u[0] = pk2bf(ra[0].x, ra[0].y); w0.u[1] = pk2bf(ra[0].z, ra[0].w);
        w0.u[2] = pk2bf(ra[1].x, ra[1].y); w0.u[3] = pk2bf(ra[1].z, ra[1].w);
        w1.u[0] = pk2bf(ra[2].x, ra[2].y); w1.u[1] = pk2bf(ra[2].z, ra[2].w);
        w1.u[2] = pk2bf(ra[3].x, ra[3].y); w1.u[3] = pk2bf(ra[3].z, ra[3].w);
        *(short8*)a = w0.v; *(short8*)(a + 8) = w1.v;
#pragma unroll
        for (int j = 0; j < 4; ++j) {
            int col = bcol + j;
            int kk = bkr ^ (((col >> 3) & 3) << 3);
            *(unsigned*)&Bs[b][bmat][col * 40 + kk] = pk2bf(rw[0][j], rw[1][j]);
        }
    };
    auto compute = [&](int b) {
        short8 af[2];
#pragma unroll
        for (int ms = 0; ms < 2; ++ms)
            af[ms] = *(const short8*)&As[b][(wid * 32 + ms * 16 + nl) * 40 + q * 8];
#pragma unroll
        for (int ns = 0; ns < 2; ++ns) {
            int col = ns * 16 + nl;
            int colb = col * 40 + 8 * (q ^ ((col >> 3) & 3));
            short8 bg = *(const short8*)&Bs[b][0][colb];
            short8 bu = *(const short8*)&Bs[b][1][colb];
#pragma unroll
            for (int ms = 0; ms < 2; ++ms) {
                accG[ms][ns] = __builtin_amdgcn_mfma_f32_16x16x32_bf16(af[ms], bg, accG[ms][ns], 0, 0, 0);
                accU[ms][ns] = __builtin_amdgcn_mfma_f32_16x16x32_bf16(af[ms], bu, accU[ms][ns], 0, 0, 0);
            }
        }
    };

    loadG(0);
    writeL(0);
    __syncthreads();
    for (int t = 0; t < D_DIM / 32; ++t) {
        int b = t & 1;
        if (t < D_DIM / 32 - 1) loadG((t + 1) * 32);
        compute(b);
        if (t < D_DIM / 32 - 1) writeL(b ^ 1);
        __syncthreads();
    }

    // epilogue: silu(g)*u -> bf16 ; D layout: col=lane&15, row=(lane>>4)*4+j
#pragma unroll
    for (int ms = 0; ms < 2; ++ms)
#pragma unroll
        for (int j = 0; j < 4; ++j) {
            int g2 = m0 + wid * 32 + ms * 16 + q * 4 + j;
            if (g2 < n_e) {
                size_t hbase = (size_t)(off + g2) * F_DIM;
#pragma unroll
                for (int ns = 0; ns < 2; ++ns) {
                    float g = accG[ms][ns][j];
                    float u = accU[ms][ns][j];
                    float hv = (g / (1.f + __expf(-g))) * u;
                    hbuf[hbase + n0 + ns * 16 + nl] = __float2bfloat16(hv);
                }
            }
        }
}

// ================= down grouped GEMM + weighted atomic combine =================
// tile 128(slots) x 32(D), BK=32, 4 waves each 32x32, R5 structure.
__global__ __launch_bounds__(256, 4) void k_down(const __hip_bfloat16* __restrict__ hbuf,
                                                 const float* __restrict__ wd_all,
                                                 const int* __restrict__ offsets,
                                                 const int* __restrict__ token_ids,
                                                 const float* __restrict__ slot_w,
                                                 float* __restrict__ y) {
    int e = blockIdx.z;
    int off = offsets[e];
    int n_e = offsets[e + 1] - off;
    int m0 = blockIdx.y * 128;
    if (m0 >= n_e) return;
    int n0 = blockIdx.x * 32;
    const float* wd = wd_all + (size_t)e * (F_DIM * D_DIM);

    __shared__ unsigned short As[2][128 * 40];
    __shared__ unsigned short Bs[2][32 * 40];

    int tid = threadIdx.x;
    int wid = tid >> 6, lane = tid & 63;
    int q = lane >> 4, nl = lane & 15;

    int arow = tid >> 1, acg = (tid & 1) * 16;
    int ag = m0 + arow;
    bool avalid = ag < n_e;
    const unsigned short* hrow = (const unsigned short*)hbuf + (size_t)(off + (avalid ? ag : 0)) * F_DIM;
    // B staging: threads 0-127 only (wave-uniform half)
    int t7 = tid & 127;
    int bkr = (t7 >> 3) * 2;
    int bcol = (t7 & 7) * 4;
    bool bact = tid < 128;

    short8 rh[2];
    f32x4 rd[2];
    f32x4 acc[2][2];
#pragma unroll
    for (int ms = 0; ms < 2; ++ms)
#pragma unroll
        for (int ns = 0; ns < 2; ++ns) acc[ms][ns] = (f32x4){0.f, 0.f, 0.f, 0.f};

    auto loadG = [&](int k0) {
        if (avalid) {
            rh[0] = *(const short8*)(hrow + k0 + acg);
            rh[1] = *(const short8*)(hrow + k0 + acg + 8);
        } else {
            rh[0] = (short8){0, 0, 0, 0, 0, 0, 0, 0};
            rh[1] = (short8){0, 0, 0, 0, 0, 0, 0, 0};
        }
        if (bact) {
            size_t o0 = (size_t)(k0 + bkr) * D_DIM + n0 + bcol;
            rd[0] = *(const f32x4*)(wd + o0);
            rd[1] = *(const f32x4*)(wd + o0 + D_DIM);
        }
    };
    auto writeL = [&](int b) {
        unsigned short* a = &As[b][arow * 40 + acg];
        *(short8*)a = rh[0]; *(short8*)(a + 8) = rh[1];
        if (bact) {
#pragma unroll
            for (int j = 0; j < 4; ++j) {
                int col = bcol + j;
                int kk = bkr ^ (((col >> 3) & 3) << 3);
                *(unsigned*)&Bs[b][col * 40 + kk] = pk2bf(rd[0][j], rd[1][j]);
            }
        }
    };
    auto compute = [&](int b) {
        short8 af[2];
#pragma unroll
        for (int ms = 0; ms < 2; ++ms)
            af[ms] = *(const short8*)&As[b][(wid * 32 + ms * 16 + nl) * 40 + q * 8];
#pragma unroll
        for (int ns = 0; ns < 2; ++ns) {
            int col = ns * 16 + nl;
            short8 bd = *(const short8*)&Bs[b][col * 40 + 8 * (q ^ ((col >> 3) & 3))];
#pragma unroll
            for (int ms = 0; ms < 2; ++ms)
                acc[ms][ns] = __builtin_amdgcn_mfma_f32_16x16x32_bf16(af[ms], bd, acc[ms][ns], 0, 0, 0);
        }
    };

    loadG(0);
    writeL(0);
    __syncthreads();
    for (int t = 0; t < F_DIM / 32; ++t) {
        int b = t & 1;
        if (t < F_DIM / 32 - 1) loadG((t + 1) * 32);
        compute(b);
        if (t < F_DIM / 32 - 1) writeL(b ^ 1);
        __syncthreads();
    }

#pragma unroll
    for (int ms = 0; ms < 2; ++ms)
#pragma unroll
        for (int j = 0; j < 4; ++j) {
            int g2 = m0 + wid * 32 + ms * 16 + q * 4 + j;
            if (g2 < n_e) {
                float w2 = slot_w[off + g2];
                int t = token_ids[off + g2];
#pragma unroll
                for (int ns = 0; ns < 2; ++ns)
                    atomicAdd(&y[(size_t)t * D_DIM + n0 + ns * 16 + nl], acc[ms][ns][j] * w2);
            }
        }
}

extern "C" void kernel_launch(void* const* d_in, const int* in_sizes, int n_in,
                              void* d_out, int out_size, void* d_ws, size_t ws_size,
                              hipStream_t stream) {
    const float* x      = (const float*)d_in[0];
    const float* w_gate = (const float*)d_in[1];
    const float* w_g    = (const float*)d_in[2];
    const float* w_u    = (const float*)d_in[3];
    const float* w_d    = (const float*)d_in[4];
    const float* bias   = (const float*)d_in[5];
    float* y = (float*)d_out;

    char* ws = (char*)d_ws;
    int*   counts    = (int*)(ws + 0);
    int*   offsets   = (int*)(ws + 64);
    int*   cursors   = (int*)(ws + 192);
    int*   topk_idx  = (int*)(ws + 256);
    float* topk_w    = (float*)(ws + 256 + 16384);
    int*   token_ids = (int*)(ws + 256 + 32768);
    float* slot_w    = (float*)(ws + 256 + 49152);
    __hip_bfloat16* hbuf = (__hip_bfloat16*)(ws + 66048);   // 4096*1024 bf16

    hipMemsetAsync(ws, 0, 256, stream);
    hipMemsetAsync(d_out, 0, (size_t)out_size * sizeof(float), stream);

    k_route<<<T_TOK, 64, 0, stream>>>(x, w_gate, bias, topk_idx, topk_w, counts);
    k_offsets<<<1, 64, 0, stream>>>(counts, offsets, cursors);
    k_scatter<<<(T_TOK * 2 + 255) / 256, 256, 0, stream>>>(topk_idx, topk_w, cursors, token_ids, slot_w);
    k_gateup<<<dim3(F_DIM / 32, 16, E_NUM), 256, 0, stream>>>(x, w_g, w_u, offsets, token_ids, hbuf);
    k_down<<<dim3(D_DIM / 32, 16, E_NUM), 256, 0, stream>>>(hbuf, w_d, offsets, token_ids, slot_w, y);
}

// Round 10
// 421.932 us; speedup vs baseline: 1.3241x; 1.0170x over previous
//
#include <hip/hip_runtime.h>
#include <hip/hip_bf16.h>

#define D_DIM 2048
#define F_DIM 1024
#define E_NUM 16
#define T_TOK 2048
#define NSLOT (T_TOK * 2)

typedef float f32x4 __attribute__((ext_vector_type(4)));
typedef short short8 __attribute__((ext_vector_type(8)));
typedef unsigned uint2v __attribute__((ext_vector_type(2)));

__device__ inline unsigned pk2bf(float a, float b) {
    __hip_bfloat162 h2 = __float22bfloat162_rn(make_float2(a, b));
    union { __hip_bfloat162 h; unsigned u; } c; c.h = h2; return c.u;
}

// ---------------- routing: 1 wave per token ----------------
__global__ __launch_bounds__(64) void k_route(const float* __restrict__ x,
                                              const float* __restrict__ wg,
                                              const float* __restrict__ bias,
                                              int* __restrict__ topk_idx,
                                              float* __restrict__ topk_w,
                                              int* __restrict__ counts) {
    int t = blockIdx.x;
    int l = threadIdx.x;
    int e = l & 15, c = l >> 4;
    const float* xr = x + (size_t)t * D_DIM + c * (D_DIM / 4);
    const float* wr = wg + (size_t)(c * (D_DIM / 4)) * E_NUM + e;
    float acc = 0.f;
#pragma unroll 4
    for (int d = 0; d < D_DIM / 4; ++d) acc += xr[d] * wr[(size_t)d * E_NUM];
    acc += __shfl_xor(acc, 16);
    acc += __shfl_xor(acc, 32);
    float m = acc;
#pragma unroll
    for (int s = 1; s < 16; s <<= 1) m = fmaxf(m, __shfl_xor(m, s));
    float p = __expf(acc - m);
    float sum = p;
#pragma unroll
    for (int s = 1; s < 16; s <<= 1) sum += __shfl_xor(sum, s);
    p = p / sum + bias[e];
    float v1 = p; int i1 = e;
#pragma unroll
    for (int s = 1; s < 16; s <<= 1) {
        float ov = __shfl_xor(v1, s); int oi = __shfl_xor(i1, s);
        if (ov > v1 || (ov == v1 && oi < i1)) { v1 = ov; i1 = oi; }
    }
    float v2 = (e == i1) ? -1e30f : p; int i2 = e;
#pragma unroll
    for (int s = 1; s < 16; s <<= 1) {
        float ov = __shfl_xor(v2, s); int oi = __shfl_xor(i2, s);
        if (ov > v2 || (ov == v2 && oi < i2)) { v2 = ov; i2 = oi; }
    }
    if (l == 0) {
        float s2 = v1 + v2 + 1e-20f;
        topk_idx[2 * t] = i1; topk_idx[2 * t + 1] = i2;
        topk_w[2 * t] = v1 / s2; topk_w[2 * t + 1] = v2 / s2;
        atomicAdd(&counts[i1], 1);
        atomicAdd(&counts[i2], 1);
    }
}

__global__ void k_offsets(const int* __restrict__ counts, int* __restrict__ offsets,
                          int* __restrict__ cursors) {
    if (threadIdx.x == 0) {
        int run = 0;
        for (int e = 0; e < E_NUM; ++e) { offsets[e] = run; cursors[e] = run; run += counts[e]; }
        offsets[E_NUM] = run;
    }
}

__global__ void k_scatter(const int* __restrict__ topk_idx, const float* __restrict__ topk_w,
                          int* __restrict__ cursors, int* __restrict__ token_ids,
                          float* __restrict__ slot_w) {
    int i = blockIdx.x * blockDim.x + threadIdx.x;
    if (i >= NSLOT) return;
    int e = topk_idx[i];
    int slot = atomicAdd(&cursors[e], 1);
    token_ids[slot] = i >> 1;
    slot_w[slot] = topk_w[i];
}

// ---------------- gather + fp32->bf16 convert of routed x rows ----------------
// xg[slot][k] bf16; one block per slot, 256 threads x 8 elems.
__global__ __launch_bounds__(256) void k_gather(const float* __restrict__ x,
                                                const int* __restrict__ token_ids,
                                                __hip_bfloat16* __restrict__ xg) {
    int s = blockIdx.x;
    const float* src = x + (size_t)token_ids[s] * D_DIM + threadIdx.x * 8;
    f32x4 a = *(const f32x4*)src;
    f32x4 b = *(const f32x4*)(src + 4);
    union { short8 v; unsigned u[4]; } w;
    w.u[0] = pk2bf(a.x, a.y); w.u[1] = pk2bf(a.z, a.w);
    w.u[2] = pk2bf(b.x, b.y); w.u[3] = pk2bf(b.z, b.w);
    *(short8*)((unsigned short*)xg + (size_t)s * D_DIM + threadIdx.x * 8) = w.v;
}

// ================= gate+up grouped GEMM =================
// tile 128(slots) x 128(F), BK=32, 8 waves (2m x 4n, each 64x32), double-buffered,
// compiler-scheduled loop (R5 structure). A from pre-gathered bf16 xg (8KB/step);
// W staged fp32->bf16 (32KB/step). 40KB staged / 2.1 MFLOP per block-step.
// A LDS: [128 rows][32 k] bf16, stride 40 shorts.
// B LDS: K-major [128 cols][32 k] bf16, stride 40, R5-verified XOR swizzle:
//   element (col,k) at col*40 + (k ^ (((col>>3)&3)<<3)); read b128 at 8*(q^((col>>3)&3)).
__global__ __launch_bounds__(512, 2) void k_gateup(const __hip_bfloat16* __restrict__ xg,
                                                   const float* __restrict__ wg_all,
                                                   const float* __restrict__ wu_all,
                                                   const int* __restrict__ offsets,
                                                   __hip_bfloat16* __restrict__ hbuf) {
    int e = blockIdx.z;
    int off = offsets[e];
    int n_e = offsets[e + 1] - off;
    int m0 = blockIdx.y * 128;
    if (m0 >= n_e) return;
    int n0 = blockIdx.x * 128;
    const float* wg = wg_all + (size_t)e * (D_DIM * F_DIM);
    const float* wu = wu_all + (size_t)e * (D_DIM * F_DIM);

    __shared__ unsigned short As[2][128 * 40];        // 10 KB x2
    __shared__ unsigned short Bs[2][2][128 * 40];     // 20 KB x2

    int tid = threadIdx.x;
    int wid = tid >> 6, lane = tid & 63;
    int q = lane >> 4, nl = lane & 15;
    int wm = wid >> 2, wn = wid & 3;                  // 2 x 4 wave grid

    // A staging: 4 threads/row, one short8 each (bf16 direct copy)
    int arow = tid >> 2, acg = (tid & 3) * 8;
    int sg = off + m0 + arow; if (sg > NSLOT - 1) sg = NSLOT - 1;
    const unsigned short* xrow = (const unsigned short*)xg + (size_t)sg * D_DIM;

    // B staging: threads 0-255 -> Wg, 256-511 -> Wu (wave-uniform).
    // Within 256: col-group (t8&31)*4, k-quad (t8>>5)*4.
    int bmat = tid >> 8;
    int t8 = tid & 255;
    int bcol = (t8 & 31) * 4;
    int bk4 = (t8 >> 5) * 4;
    const float* wmat = bmat ? wu : wg;

    short8 rA;
    f32x4 rw[4];
    f32x4 accG[4][2], accU[4][2];
#pragma unroll
    for (int ms = 0; ms < 4; ++ms)
#pragma unroll
        for (int ns = 0; ns < 2; ++ns) {
            accG[ms][ns] = (f32x4){0.f, 0.f, 0.f, 0.f};
            accU[ms][ns] = (f32x4){0.f, 0.f, 0.f, 0.f};
        }

    auto loadG = [&](int k0) {
        rA = *(const short8*)(xrow + k0 + acg);
        const float* p = wmat + (size_t)(k0 + bk4) * F_DIM + n0 + bcol;
#pragma unroll
        for (int i = 0; i < 4; ++i) rw[i] = *(const f32x4*)(p + (size_t)i * F_DIM);
    };
    auto writeL = [&](int b) {
        *(short8*)&As[b][arow * 40 + acg] = rA;
#pragma unroll
        for (int j = 0; j < 4; ++j) {
            int col = bcol + j;
            int kk = bk4 ^ (((col >> 3) & 3) << 3);
            uint2v v;
            v[0] = pk2bf(rw[0][j], rw[1][j]);
            v[1] = pk2bf(rw[2][j], rw[3][j]);
            *(uint2v*)&Bs[b][bmat][col * 40 + kk] = v;
        }
    };
    auto compute = [&](int b) {
        short8 af[4];
#pragma unroll
        for (int ms = 0; ms < 4; ++ms)
            af[ms] = *(const short8*)&As[b][(wm * 64 + ms * 16 + nl) * 40 + q * 8];
#pragma unroll
        for (int ns = 0; ns < 2; ++ns) {
            int col = wn * 32 + ns * 16 + nl;
            int colb = col * 40 + 8 * (q ^ ((col >> 3) & 3));
            short8 bg = *(const short8*)&Bs[b][0][colb];
            short8 bu = *(const short8*)&Bs[b][1][colb];
#pragma unroll
            for (int ms = 0; ms < 4; ++ms) {
                accG[ms][ns] = __builtin_amdgcn_mfma_f32_16x16x32_bf16(af[ms], bg, accG[ms][ns], 0, 0, 0);
                accU[ms][ns] = __builtin_amdgcn_mfma_f32_16x16x32_bf16(af[ms], bu, accU[ms][ns], 0, 0, 0);
            }
        }
    };

    loadG(0);
    writeL(0);
    __syncthreads();
    for (int t = 0; t < D_DIM / 32; ++t) {
        int b = t & 1;
        if (t < D_DIM / 32 - 1) loadG((t + 1) * 32);
        compute(b);
        if (t < D_DIM / 32 - 1) writeL(b ^ 1);
        __syncthreads();
    }

    // epilogue: silu(g)*u -> bf16 ; D layout: col=lane&15, row=(lane>>4)*4+j
#pragma unroll
    for (int ms = 0; ms < 4; ++ms)
#pragma unroll
        for (int j = 0; j < 4; ++j) {
            int r = m0 + wm * 64 + ms * 16 + q * 4 + j;
            if (r < n_e) {
                size_t hbase = (size_t)(off + r) * F_DIM;
#pragma unroll
                for (int ns = 0; ns < 2; ++ns) {
                    float g = accG[ms][ns][j];
                    float u = accU[ms][ns][j];
                    float hv = (g / (1.f + __expf(-g))) * u;
                    hbuf[hbase + n0 + wn * 32 + ns * 16 + nl] = __float2bfloat16(hv);
                }
            }
        }
}

// ================= down grouped GEMM + weighted atomic combine =================
// tile 128(slots) x 128(D), BK=32, 8 waves (2m x 4n), same structure.
__global__ __launch_bounds__(512, 4) void k_down(const __hip_bfloat16* __restrict__ hbuf,
                                                 const float* __restrict__ wd_all,
                                                 const int* __restrict__ offsets,
                                                 const int* __restrict__ token_ids,
                                                 const float* __restrict__ slot_w,
                                                 float* __restrict__ y) {
    int e = blockIdx.z;
    int off = offsets[e];
    int n_e = offsets[e + 1] - off;
    int m0 = blockIdx.y * 128;
    if (m0 >= n_e) return;
    int n0 = blockIdx.x * 128;
    const float* wd = wd_all + (size_t)e * (F_DIM * D_DIM);

    __shared__ unsigned short As[2][128 * 40];
    __shared__ unsigned short Bs[2][128 * 40];

    int tid = threadIdx.x;
    int wid = tid >> 6, lane = tid & 63;
    int q = lane >> 4, nl = lane & 15;
    int wm = wid >> 2, wn = wid & 3;

    int arow = tid >> 2, acg = (tid & 3) * 8;
    int sg = off + m0 + arow; if (sg > NSLOT - 1) sg = NSLOT - 1;
    const unsigned short* hrow = (const unsigned short*)hbuf + (size_t)sg * F_DIM;

    // B staging: 512 threads: col-group (tid&31)*4, k-pair (tid>>5)*2
    int bcol = (tid & 31) * 4;
    int bk2 = (tid >> 5) * 2;

    short8 rA;
    f32x4 rd[2];
    f32x4 acc[4][2];
#pragma unroll
    for (int ms = 0; ms < 4; ++ms)
#pragma unroll
        for (int ns = 0; ns < 2; ++ns) acc[ms][ns] = (f32x4){0.f, 0.f, 0.f, 0.f};

    auto loadG = [&](int k0) {
        rA = *(const short8*)(hrow + k0 + acg);
        size_t o0 = (size_t)(k0 + bk2) * D_DIM + n0 + bcol;
        rd[0] = *(const f32x4*)(wd + o0);
        rd[1] = *(const f32x4*)(wd + o0 + D_DIM);
    };
    auto writeL = [&](int b) {
        *(short8*)&As[b][arow * 40 + acg] = rA;
#pragma unroll
        for (int j = 0; j < 4; ++j) {
            int col = bcol + j;
            int kk = bk2 ^ (((col >> 3) & 3) << 3);
            *(unsigned*)&Bs[b][col * 40 + kk] = pk2bf(rd[0][j], rd[1][j]);
        }
    };
    auto compute = [&](int b) {
        short8 af[4];
#pragma unroll
        for (int ms = 0; ms < 4; ++ms)
            af[ms] = *(const short8*)&As[b][(wm * 64 + ms * 16 + nl) * 40 + q * 8];
#pragma unroll
        for (int ns = 0; ns < 2; ++ns) {
            int col = wn * 32 + ns * 16 + nl;
            short8 bd = *(const short8*)&Bs[b][col * 40 + 8 * (q ^ ((col >> 3) & 3))];
#pragma unroll
            for (int ms = 0; ms < 4; ++ms)
                acc[ms][ns] = __builtin_amdgcn_mfma_f32_16x16x32_bf16(af[ms], bd, acc[ms][ns], 0, 0, 0);
        }
    };

    loadG(0);
    writeL(0);
    __syncthreads();
    for (int t = 0; t < F_DIM / 32; ++t) {
        int b = t & 1;
        if (t < F_DIM / 32 - 1) loadG((t + 1) * 32);
        compute(b);
        if (t < F_DIM / 32 - 1) writeL(b ^ 1);
        __syncthreads();
    }

#pragma unroll
    for (int ms = 0; ms < 4; ++ms)
#pragma unroll
        for (int j = 0; j < 4; ++j) {
            int r = m0 + wm * 64 + ms * 16 + q * 4 + j;
            if (r < n_e) {
                float w2 = slot_w[off + r];
                int t = token_ids[off + r];
#pragma unroll
                for (int ns = 0; ns < 2; ++ns)
                    atomicAdd(&y[(size_t)t * D_DIM + n0 + wn * 32 + ns * 16 + nl], acc[ms][ns][j] * w2);
            }
        }
}

extern "C" void kernel_launch(void* const* d_in, const int* in_sizes, int n_in,
                              void* d_out, int out_size, void* d_ws, size_t ws_size,
                              hipStream_t stream) {
    const float* x      = (const float*)d_in[0];
    const float* w_gate = (const float*)d_in[1];
    const float* w_g    = (const float*)d_in[2];
    const float* w_u    = (const float*)d_in[3];
    const float* w_d    = (const float*)d_in[4];
    const float* bias   = (const float*)d_in[5];
    float* y = (float*)d_out;

    char* ws = (char*)d_ws;
    int*   counts    = (int*)(ws + 0);
    int*   offsets   = (int*)(ws + 64);
    int*   cursors   = (int*)(ws + 192);
    int*   topk_idx  = (int*)(ws + 256);
    float* topk_w    = (float*)(ws + 256 + 16384);
    int*   token_ids = (int*)(ws + 256 + 32768);
    float* slot_w    = (float*)(ws + 256 + 49152);
    __hip_bfloat16* hbuf = (__hip_bfloat16*)(ws + 66048);                 // 4096*1024 bf16 = 8 MB
    __hip_bfloat16* xg   = (__hip_bfloat16*)(ws + 66048 + 8388608);      // 4096*2048 bf16 = 16 MB

    hipMemsetAsync(ws, 0, 256, stream);
    hipMemsetAsync(d_out, 0, (size_t)out_size * sizeof(float), stream);

    k_route<<<T_TOK, 64, 0, stream>>>(x, w_gate, bias, topk_idx, topk_w, counts);
    k_offsets<<<1, 64, 0, stream>>>(counts, offsets, cursors);
    k_scatter<<<(NSLOT + 255) / 256, 256, 0, stream>>>(topk_idx, topk_w, cursors, token_ids, slot_w);
    k_gather<<<NSLOT, 256, 0, stream>>>(x, token_ids, xg);
    k_gateup<<<dim3(F_DIM / 128, 16, E_NUM), 512, 0, stream>>>(xg, w_g, w_u, offsets, hbuf);
    k_down<<<dim3(D_DIM / 128, 16, E_NUM), 512, 0, stream>>>(hbuf, w_d, offsets, token_ids, slot_w, y);
}

// Round 11
// 375.241 us; speedup vs baseline: 1.4889x; 1.1244x over previous
//
#include <hip/hip_runtime.h>
#include <hip/hip_bf16.h>

#define D_DIM 2048
#define F_DIM 1024
#define E_NUM 16
#define T_TOK 2048
#define NSLOT (T_TOK * 2)

typedef float f32x4 __attribute__((ext_vector_type(4)));
typedef short short8 __attribute__((ext_vector_type(8)));

__device__ inline unsigned pk2bf(float a, float b) {
    __hip_bfloat162 h2 = __float22bfloat162_rn(make_float2(a, b));
    union { __hip_bfloat162 h; unsigned u; } c; c.h = h2; return c.u;
}

// ---------------- routing: 1 wave per token ----------------
__global__ __launch_bounds__(64) void k_route(const float* __restrict__ x,
                                              const float* __restrict__ wg,
                                              const float* __restrict__ bias,
                                              int* __restrict__ topk_idx,
                                              float* __restrict__ topk_w,
                                              int* __restrict__ counts) {
    int t = blockIdx.x;
    int l = threadIdx.x;
    int e = l & 15, c = l >> 4;
    const float* xr = x + (size_t)t * D_DIM + c * (D_DIM / 4);
    const float* wr = wg + (size_t)(c * (D_DIM / 4)) * E_NUM + e;
    float acc = 0.f;
#pragma unroll 4
    for (int d = 0; d < D_DIM / 4; ++d) acc += xr[d] * wr[(size_t)d * E_NUM];
    acc += __shfl_xor(acc, 16);
    acc += __shfl_xor(acc, 32);
    float m = acc;
#pragma unroll
    for (int s = 1; s < 16; s <<= 1) m = fmaxf(m, __shfl_xor(m, s));
    float p = __expf(acc - m);
    float sum = p;
#pragma unroll
    for (int s = 1; s < 16; s <<= 1) sum += __shfl_xor(sum, s);
    p = p / sum + bias[e];
    float v1 = p; int i1 = e;
#pragma unroll
    for (int s = 1; s < 16; s <<= 1) {
        float ov = __shfl_xor(v1, s); int oi = __shfl_xor(i1, s);
        if (ov > v1 || (ov == v1 && oi < i1)) { v1 = ov; i1 = oi; }
    }
    float v2 = (e == i1) ? -1e30f : p; int i2 = e;
#pragma unroll
    for (int s = 1; s < 16; s <<= 1) {
        float ov = __shfl_xor(v2, s); int oi = __shfl_xor(i2, s);
        if (ov > v2 || (ov == v2 && oi < i2)) { v2 = ov; i2 = oi; }
    }
    if (l == 0) {
        float s2 = v1 + v2 + 1e-20f;
        topk_idx[2 * t] = i1; topk_idx[2 * t + 1] = i2;
        topk_w[2 * t] = v1 / s2; topk_w[2 * t + 1] = v2 / s2;
        atomicAdd(&counts[i1], 1);
        atomicAdd(&counts[i2], 1);
    }
}

__global__ void k_offsets(const int* __restrict__ counts, int* __restrict__ offsets,
                          int* __restrict__ cursors) {
    if (threadIdx.x == 0) {
        int run = 0;
        for (int e = 0; e < E_NUM; ++e) { offsets[e] = run; cursors[e] = run; run += counts[e]; }
        offsets[E_NUM] = run;
    }
}

__global__ void k_scatter(const int* __restrict__ topk_idx, const float* __restrict__ topk_w,
                          int* __restrict__ cursors, int* __restrict__ token_ids,
                          float* __restrict__ slot_w) {
    int i = blockIdx.x * blockDim.x + threadIdx.x;
    if (i >= NSLOT) return;
    int e = topk_idx[i];
    int slot = atomicAdd(&cursors[e], 1);
    token_ids[slot] = i >> 1;
    slot_w[slot] = topk_w[i];
}

// ---------------- gather + fp32->bf16 convert of routed x rows ----------------
__global__ __launch_bounds__(256) void k_gather(const float* __restrict__ x,
                                                const int* __restrict__ token_ids,
                                                __hip_bfloat16* __restrict__ xg) {
    int s = blockIdx.x;
    const float* src = x + (size_t)token_ids[s] * D_DIM + threadIdx.x * 8;
    f32x4 a = *(const f32x4*)src;
    f32x4 b = *(const f32x4*)(src + 4);
    union { short8 v; unsigned u[4]; } w;
    w.u[0] = pk2bf(a.x, a.y); w.u[1] = pk2bf(a.z, a.w);
    w.u[2] = pk2bf(b.x, b.y); w.u[3] = pk2bf(b.z, b.w);
    *(short8*)((unsigned short*)xg + (size_t)s * D_DIM + threadIdx.x * 8) = w.v;
}

// ================= gate+up grouped GEMM =================
// R7's proven 2.7TB/s config: tile 64x64, BK=32, 4 waves (2x2, each 32x32),
// double-buffered, compiler-scheduled, 30KB LDS, 4 blocks/CU.
// + XCD-chunked swizzle, m innermost: all 32 same-W m-blocks on one XCD -> W L2-hit.
// + A operand from pre-gathered bf16 xg (copy, no convert).
// B LDS: K-major [64 cols][32 k], stride 40, verified XOR swizzle.
__global__ __launch_bounds__(256, 4) void k_gateup(const __hip_bfloat16* __restrict__ xg,
                                                   const float* __restrict__ wg_all,
                                                   const float* __restrict__ wu_all,
                                                   const int* __restrict__ offsets,
                                                   __hip_bfloat16* __restrict__ hbuf) {
    // 8192 blocks: w = e*512 + ni*32 + mi ; XCD-chunked (1024/XCD, divisible)
    unsigned b0 = blockIdx.x;
    unsigned w = (b0 & 7) * 1024u + (b0 >> 3);
    int mi = w & 31;
    int ni = (w >> 5) & 15;
    int e  = w >> 9;
    int off = offsets[e];
    int n_e = offsets[e + 1] - off;
    int m0 = mi * 64;
    if (m0 >= n_e) return;
    int n0 = ni * 64;
    const float* wg = wg_all + (size_t)e * (D_DIM * F_DIM);
    const float* wu = wu_all + (size_t)e * (D_DIM * F_DIM);

    __shared__ unsigned short As[2][64 * 40];
    __shared__ unsigned short Bs[2][2][64 * 40];

    int tid = threadIdx.x;
    int wid = tid >> 6, lane = tid & 63;
    int q = lane >> 4, nl = lane & 15;
    int wr = wid >> 1, wc = wid & 1;

    // A staging: 4 threads/row, one short8 each (bf16 copy from xg)
    int arow = tid >> 2, acg = (tid & 3) * 8;
    int sg = off + m0 + arow; if (sg > NSLOT - 1) sg = NSLOT - 1;
    const unsigned short* xrow = (const unsigned short*)xg + (size_t)sg * D_DIM;
    // B staging: k-pair rows {bkr,bkr+1}, cols bcol..bcol+3 (float4 loads, R7 pattern)
    int bkr = (tid >> 4) * 2;
    int bcol = (tid & 15) * 4;

    short8 rA;
    f32x4 rg[2], ru[2];
    f32x4 accG[2][2], accU[2][2];
#pragma unroll
    for (int ms = 0; ms < 2; ++ms)
#pragma unroll
        for (int ns = 0; ns < 2; ++ns) {
            accG[ms][ns] = (f32x4){0.f, 0.f, 0.f, 0.f};
            accU[ms][ns] = (f32x4){0.f, 0.f, 0.f, 0.f};
        }

    auto loadG = [&](int k0) {
        rA = *(const short8*)(xrow + k0 + acg);
        size_t o0 = (size_t)(k0 + bkr) * F_DIM + n0 + bcol;
        rg[0] = *(const f32x4*)(wg + o0);
        rg[1] = *(const f32x4*)(wg + o0 + F_DIM);
        ru[0] = *(const f32x4*)(wu + o0);
        ru[1] = *(const f32x4*)(wu + o0 + F_DIM);
    };
    auto writeL = [&](int b) {
        *(short8*)&As[b][arow * 40 + acg] = rA;
#pragma unroll
        for (int j = 0; j < 4; ++j) {
            int col = bcol + j;
            int kk = bkr ^ (((col >> 3) & 3) << 3);
            *(unsigned*)&Bs[b][0][col * 40 + kk] = pk2bf(rg[0][j], rg[1][j]);
            *(unsigned*)&Bs[b][1][col * 40 + kk] = pk2bf(ru[0][j], ru[1][j]);
        }
    };
    auto compute = [&](int b) {
        short8 af[2];
#pragma unroll
        for (int ms = 0; ms < 2; ++ms)
            af[ms] = *(const short8*)&As[b][(wr * 32 + ms * 16 + nl) * 40 + q * 8];
#pragma unroll
        for (int ns = 0; ns < 2; ++ns) {
            int col = wc * 32 + ns * 16 + nl;
            int colb = col * 40 + 8 * (q ^ ((col >> 3) & 3));
            short8 bg = *(const short8*)&Bs[b][0][colb];
            short8 bu = *(const short8*)&Bs[b][1][colb];
#pragma unroll
            for (int ms = 0; ms < 2; ++ms) {
                accG[ms][ns] = __builtin_amdgcn_mfma_f32_16x16x32_bf16(af[ms], bg, accG[ms][ns], 0, 0, 0);
                accU[ms][ns] = __builtin_amdgcn_mfma_f32_16x16x32_bf16(af[ms], bu, accU[ms][ns], 0, 0, 0);
            }
        }
    };

    loadG(0);
    writeL(0);
    __syncthreads();
    for (int t = 0; t < D_DIM / 32; ++t) {
        int b = t & 1;
        if (t < D_DIM / 32 - 1) loadG((t + 1) * 32);
        compute(b);
        if (t < D_DIM / 32 - 1) writeL(b ^ 1);
        __syncthreads();
    }

    // epilogue: silu(g)*u -> bf16 ; D layout: col=lane&15, row=(lane>>4)*4+j
#pragma unroll
    for (int ms = 0; ms < 2; ++ms)
#pragma unroll
        for (int j = 0; j < 4; ++j) {
            int g2 = m0 + wr * 32 + ms * 16 + q * 4 + j;
            if (g2 < n_e) {
                size_t hbase = (size_t)(off + g2) * F_DIM;
#pragma unroll
                for (int ns = 0; ns < 2; ++ns) {
                    float g = accG[ms][ns][j];
                    float u = accU[ms][ns][j];
                    float hv = (g / (1.f + __expf(-g))) * u;
                    hbuf[hbase + n0 + wc * 32 + ns * 16 + nl] = __float2bfloat16(hv);
                }
            }
        }
}

// ================= down grouped GEMM + weighted atomic combine =================
// Same R7 structure + XCD swizzle (m innermost).
__global__ __launch_bounds__(256, 4) void k_down(const __hip_bfloat16* __restrict__ hbuf,
                                                 const float* __restrict__ wd_all,
                                                 const int* __restrict__ offsets,
                                                 const int* __restrict__ token_ids,
                                                 const float* __restrict__ slot_w,
                                                 float* __restrict__ y) {
    // 16384 blocks: w = e*1024 + ni*32 + mi ; XCD-chunked (2048/XCD)
    unsigned b0 = blockIdx.x;
    unsigned w = (b0 & 7) * 2048u + (b0 >> 3);
    int mi = w & 31;
    int ni = (w >> 5) & 31;
    int e  = w >> 10;
    int off = offsets[e];
    int n_e = offsets[e + 1] - off;
    int m0 = mi * 64;
    if (m0 >= n_e) return;
    int n0 = ni * 64;
    const float* wd = wd_all + (size_t)e * (F_DIM * D_DIM);

    __shared__ unsigned short As[2][64 * 40];
    __shared__ unsigned short Bs[2][64 * 40];

    int tid = threadIdx.x;
    int wid = tid >> 6, lane = tid & 63;
    int q = lane >> 4, nl = lane & 15;
    int wr = wid >> 1, wc = wid & 1;

    int arow = tid >> 2, acg = (tid & 3) * 8;
    int sg = off + m0 + arow; if (sg > NSLOT - 1) sg = NSLOT - 1;
    const unsigned short* hrow = (const unsigned short*)hbuf + (size_t)sg * F_DIM;
    int bkr = (tid >> 4) * 2;
    int bcol = (tid & 15) * 4;

    short8 rh;
    f32x4 rd[2];
    f32x4 acc[2][2];
#pragma unroll
    for (int ms = 0; ms < 2; ++ms)
#pragma unroll
        for (int ns = 0; ns < 2; ++ns) acc[ms][ns] = (f32x4){0.f, 0.f, 0.f, 0.f};

    auto loadG = [&](int k0) {
        rh = *(const short8*)(hrow + k0 + acg);
        size_t o0 = (size_t)(k0 + bkr) * D_DIM + n0 + bcol;
        rd[0] = *(const f32x4*)(wd + o0);
        rd[1] = *(const f32x4*)(wd + o0 + D_DIM);
    };
    auto writeL = [&](int b) {
        *(short8*)&As[b][arow * 40 + acg] = rh;
#pragma unroll
        for (int j = 0; j < 4; ++j) {
            int col = bcol + j;
            int kk = bkr ^ (((col >> 3) & 3) << 3);
            *(unsigned*)&Bs[b][col * 40 + kk] = pk2bf(rd[0][j], rd[1][j]);
        }
    };
    auto compute = [&](int b) {
        short8 af[2];
#pragma unroll
        for (int ms = 0; ms < 2; ++ms)
            af[ms] = *(const short8*)&As[b][(wr * 32 + ms * 16 + nl) * 40 + q * 8];
#pragma unroll
        for (int ns = 0; ns < 2; ++ns) {
            int col = wc * 32 + ns * 16 + nl;
            short8 bd = *(const short8*)&Bs[b][col * 40 + 8 * (q ^ ((col >> 3) & 3))];
#pragma unroll
            for (int ms = 0; ms < 2; ++ms)
                acc[ms][ns] = __builtin_amdgcn_mfma_f32_16x16x32_bf16(af[ms], bd, acc[ms][ns], 0, 0, 0);
        }
    };

    loadG(0);
    writeL(0);
    __syncthreads();
    for (int t = 0; t < F_DIM / 32; ++t) {
        int b = t & 1;
        if (t < F_DIM / 32 - 1) loadG((t + 1) * 32);
        compute(b);
        if (t < F_DIM / 32 - 1) writeL(b ^ 1);
        __syncthreads();
    }

#pragma unroll
    for (int ms = 0; ms < 2; ++ms)
#pragma unroll
        for (int j = 0; j < 4; ++j) {
            int g2 = m0 + wr * 32 + ms * 16 + q * 4 + j;
            if (g2 < n_e) {
                float w2 = slot_w[off + g2];
                int t = token_ids[off + g2];
#pragma unroll
                for (int ns = 0; ns < 2; ++ns)
                    atomicAdd(&y[(size_t)t * D_DIM + n0 + wc * 32 + ns * 16 + nl], acc[ms][ns][j] * w2);
            }
        }
}

extern "C" void kernel_launch(void* const* d_in, const int* in_sizes, int n_in,
                              void* d_out, int out_size, void* d_ws, size_t ws_size,
                              hipStream_t stream) {
    const float* x      = (const float*)d_in[0];
    const float* w_gate = (const float*)d_in[1];
    const float* w_g    = (const float*)d_in[2];
    const float* w_u    = (const float*)d_in[3];
    const float* w_d    = (const float*)d_in[4];
    const float* bias   = (const float*)d_in[5];
    float* y = (float*)d_out;

    char* ws = (char*)d_ws;
    int*   counts    = (int*)(ws + 0);
    int*   offsets   = (int*)(ws + 64);
    int*   cursors   = (int*)(ws + 192);
    int*   topk_idx  = (int*)(ws + 256);
    float* topk_w    = (float*)(ws + 256 + 16384);
    int*   token_ids = (int*)(ws + 256 + 32768);
    float* slot_w    = (float*)(ws + 256 + 49152);
    __hip_bfloat16* hbuf = (__hip_bfloat16*)(ws + 66048);              // 8 MB
    __hip_bfloat16* xg   = (__hip_bfloat16*)(ws + 66048 + 8388608);    // 16 MB

    hipMemsetAsync(ws, 0, 256, stream);
    hipMemsetAsync(d_out, 0, (size_t)out_size * sizeof(float), stream);

    k_route<<<T_TOK, 64, 0, stream>>>(x, w_gate, bias, topk_idx, topk_w, counts);
    k_offsets<<<1, 64, 0, stream>>>(counts, offsets, cursors);
    k_scatter<<<(NSLOT + 255) / 256, 256, 0, stream>>>(topk_idx, topk_w, cursors, token_ids, slot_w);
    k_gather<<<NSLOT, 256, 0, stream>>>(x, token_ids, xg);
    k_gateup<<<16 * 32 * E_NUM, 256, 0, stream>>>(xg, w_g, w_u, offsets, hbuf);
    k_down<<<32 * 32 * E_NUM, 256, 0, stream>>>(hbuf, w_d, offsets, token_ids, slot_w, y);
}

// Round 13
// 371.314 us; speedup vs baseline: 1.5046x; 1.0106x over previous
//
#include <hip/hip_runtime.h>
#include <hip/hip_bf16.h>

#define D_DIM 2048
#define F_DIM 1024
#define E_NUM 16
#define T_TOK 2048
#define NSLOT (T_TOK * 2)

typedef float f32x4 __attribute__((ext_vector_type(4)));
typedef short short8 __attribute__((ext_vector_type(8)));
typedef unsigned uint2v __attribute__((ext_vector_type(2)));

__device__ inline unsigned pk2bf(float a, float b) {
    __hip_bfloat162 h2 = __float22bfloat162_rn(make_float2(a, b));
    union { __hip_bfloat162 h; unsigned u; } c; c.h = h2; return c.u;
}

__device__ inline unsigned short bf16bits(float a) {
    union { __hip_bfloat16 h; unsigned short u; } c;
    c.h = __float2bfloat16(a);
    return c.u;
}

// global -> LDS direct async copy, 16B per lane. LDS dst must be wave-uniform;
// HW writes dst + lane*16 from each lane's gsrc. (m03/m97-verified on gfx950.)
typedef __attribute__((address_space(1))) const unsigned int* gas_p;
typedef __attribute__((address_space(3))) unsigned int* las_p;
__device__ __forceinline__ void gld16(const unsigned short* g, unsigned short* l) {
    __builtin_amdgcn_global_load_lds((gas_p)(const void*)g, (las_p)(void*)l, 16, 0, 0);
}

// ---------------- routing: 1 wave per token ----------------
__global__ __launch_bounds__(64) void k_route(const float* __restrict__ x,
                                              const float* __restrict__ wg,
                                              const float* __restrict__ bias,
                                              int* __restrict__ topk_idx,
                                              float* __restrict__ topk_w,
                                              int* __restrict__ counts) {
    int t = blockIdx.x;
    int l = threadIdx.x;
    int e = l & 15, c = l >> 4;
    const float* xr = x + (size_t)t * D_DIM + c * (D_DIM / 4);
    const float* wr = wg + (size_t)(c * (D_DIM / 4)) * E_NUM + e;
    float acc = 0.f;
#pragma unroll 4
    for (int d = 0; d < D_DIM / 4; ++d) acc += xr[d] * wr[(size_t)d * E_NUM];
    acc += __shfl_xor(acc, 16);
    acc += __shfl_xor(acc, 32);
    float m = acc;
#pragma unroll
    for (int s = 1; s < 16; s <<= 1) m = fmaxf(m, __shfl_xor(m, s));
    float p = __expf(acc - m);
    float sum = p;
#pragma unroll
    for (int s = 1; s < 16; s <<= 1) sum += __shfl_xor(sum, s);
    p = p / sum + bias[e];
    float v1 = p; int i1 = e;
#pragma unroll
    for (int s = 1; s < 16; s <<= 1) {
        float ov = __shfl_xor(v1, s); int oi = __shfl_xor(i1, s);
        if (ov > v1 || (ov == v1 && oi < i1)) { v1 = ov; i1 = oi; }
    }
    float v2 = (e == i1) ? -1e30f : p; int i2 = e;
#pragma unroll
    for (int s = 1; s < 16; s <<= 1) {
        float ov = __shfl_xor(v2, s); int oi = __shfl_xor(i2, s);
        if (ov > v2 || (ov == v2 && oi < i2)) { v2 = ov; i2 = oi; }
    }
    if (l == 0) {
        float s2 = v1 + v2 + 1e-20f;
        topk_idx[2 * t] = i1; topk_idx[2 * t + 1] = i2;
        topk_w[2 * t] = v1 / s2; topk_w[2 * t + 1] = v2 / s2;
        atomicAdd(&counts[i1], 1);
        atomicAdd(&counts[i2], 1);
    }
}

// offsets + padded-block (pb) tables: pb = 128-row block; pbe[pb]=expert, pbm[pb]=local idx
__global__ void k_offsets(const int* __restrict__ counts, int* __restrict__ offsets,
                          int* __restrict__ cursors, int* __restrict__ pbe,
                          int* __restrict__ pbm, int* __restrict__ npbp) {
    if (threadIdx.x == 0) {
        int run = 0, npb = 0;
        for (int e = 0; e < E_NUM; ++e) {
            offsets[e] = run; cursors[e] = run;
            int ne = counts[e];
            int nb = (ne + 127) >> 7;
            for (int i = 0; i < nb; ++i) { pbe[npb] = e; pbm[npb] = i; ++npb; }
            run += ne;
        }
        offsets[E_NUM] = run;
        npbp[0] = npb;
    }
}

__global__ void k_scatter(const int* __restrict__ topk_idx, const float* __restrict__ topk_w,
                          int* __restrict__ cursors, int* __restrict__ token_ids,
                          float* __restrict__ slot_w) {
    int i = blockIdx.x * blockDim.x + threadIdx.x;
    if (i >= NSLOT) return;
    int e = topk_idx[i];
    int slot = atomicAdd(&cursors[e], 1);
    token_ids[slot] = i >> 1;
    slot_w[slot] = topk_w[i];
}

// ---------------- gather x -> A-image [pb][ks(64)][128 rows][32 k] bf16 ----------------
__global__ __launch_bounds__(256) void k_gatherI(const float* __restrict__ x,
                                                 const int* __restrict__ token_ids,
                                                 const int* __restrict__ offsets,
                                                 const int* __restrict__ pbe,
                                                 const int* __restrict__ pbm,
                                                 const int* __restrict__ npbp,
                                                 unsigned short* __restrict__ xgI) {
    int pb = blockIdx.y;
    if (pb >= npbp[0]) return;
    int ks = blockIdx.x;
    int e = pbe[pb];
    int ne = offsets[e + 1] - offsets[e];
    int t = threadIdx.x;
    int r = t >> 1, half = (t & 1) * 16;
    int local = pbm[pb] * 128 + r;
    unsigned o[8];
    if (local < ne) {
        const float* src = x + (size_t)token_ids[offsets[e] + local] * D_DIM + ks * 32 + half;
        f32x4 a = *(const f32x4*)src;
        f32x4 b = *(const f32x4*)(src + 4);
        f32x4 c = *(const f32x4*)(src + 8);
        f32x4 d = *(const f32x4*)(src + 12);
        o[0] = pk2bf(a.x, a.y); o[1] = pk2bf(a.z, a.w);
        o[2] = pk2bf(b.x, b.y); o[3] = pk2bf(b.z, b.w);
        o[4] = pk2bf(c.x, c.y); o[5] = pk2bf(c.z, c.w);
        o[6] = pk2bf(d.x, d.y); o[7] = pk2bf(d.z, d.w);
    } else {
#pragma unroll
        for (int i = 0; i < 8; ++i) o[i] = 0;
    }
    unsigned short* dst = xgI + ((size_t)(pb * 64 + ks)) * 4096 + r * 32 + half;
    union { short8 v; unsigned u[4]; } w0, w1;
    w0.u[0] = o[0]; w0.u[1] = o[1]; w0.u[2] = o[2]; w0.u[3] = o[3];
    w1.u[0] = o[4]; w1.u[1] = o[5]; w1.u[2] = o[6]; w1.u[3] = o[7];
    *(short8*)dst = w0.v;
    *(short8*)(dst + 8) = w1.v;
}

// ---------------- prep Wg/Wu -> image [e][n32][ks64][2 mat][32 col][32 k] bf16 ----------------
__global__ __launch_bounds__(256) void k_prep_gu(const float* __restrict__ wg_all,
                                                 const float* __restrict__ wu_all,
                                                 unsigned short* __restrict__ wguI) {
    int ks = blockIdx.x, n = blockIdx.y, e = blockIdx.z;
    __shared__ float S[32][40];
    int t = threadIdx.x;
    int kk = t >> 3, cg = (t & 7) * 4;       // read map: row kk, 4 cols
    int col = t >> 3, k4 = (t & 7) * 4;      // write map: col, 4 k
    size_t rbase = (size_t)e * (D_DIM * F_DIM) + (size_t)(ks * 32) * F_DIM + n * 32;
    unsigned short* obase = wguI + ((size_t)((e * 32 + n) * 64 + ks)) * 2048;
    const float* mats[2] = { wg_all, wu_all };
#pragma unroll
    for (int m = 0; m < 2; ++m) {
        *(f32x4*)&S[kk][cg] = *(const f32x4*)(mats[m] + rbase + (size_t)kk * F_DIM + cg);
        __syncthreads();
        uint2v o;
        o[0] = pk2bf(S[k4][col], S[k4 + 1][col]);
        o[1] = pk2bf(S[k4 + 2][col], S[k4 + 3][col]);
        *(uint2v*)&obase[m * 1024 + col * 32 + k4] = o;
        __syncthreads();
    }
}

// ---------------- prep Wd -> image [e][n32][ks32][64 col][32 k] bf16 ----------------
__global__ __launch_bounds__(256) void k_prep_d(const float* __restrict__ wd_all,
                                                unsigned short* __restrict__ wdI) {
    int ks = blockIdx.x, n = blockIdx.y, e = blockIdx.z;
    __shared__ float S[32][68];
    int t = threadIdx.x;
    int kk = t >> 3, cg = (t & 7) * 8;       // read: row kk, 8 cols
    int col = t >> 2, k8 = (t & 3) * 8;      // write: col, 8 k
    size_t rbase = (size_t)e * (F_DIM * D_DIM) + (size_t)(ks * 32) * D_DIM + n * 64;
    unsigned short* obase = wdI + ((size_t)((e * 32 + n) * 32 + ks)) * 2048;
    const float* src = wd_all + rbase + (size_t)kk * D_DIM + cg;
    *(f32x4*)&S[kk][cg] = *(const f32x4*)src;
    *(f32x4*)&S[kk][cg + 4] = *(const f32x4*)(src + 4);
    __syncthreads();
    union { short8 v; unsigned u[4]; } o;
#pragma unroll
    for (int i = 0; i < 4; ++i)
        o.u[i] = pk2bf(S[k8 + 2 * i][col], S[k8 + 2 * i + 1][col]);
    *(short8*)&obase[col * 32 + k8] = o.v;
}

// ================= gate+up GEMM: images + global_load_lds, 1 barrier/step =================
// tile 128(rows) x 32(F-cols), BK=32, 4 waves (each 32x32). LDS 24KB.
__global__ __launch_bounds__(256, 6) void k_gateupI(const unsigned short* __restrict__ xgI,
                                                    const unsigned short* __restrict__ wguI,
                                                    const int* __restrict__ pbe,
                                                    const int* __restrict__ npbp,
                                                    unsigned short* __restrict__ hI) {
    int pb = blockIdx.y;
    if (pb >= npbp[0]) return;
    int n = blockIdx.x;                       // 0..31 (32-col block of F)
    int e = pbe[pb];
    __shared__ __align__(16) unsigned short A[2][4096];   // [128][32]
    __shared__ __align__(16) unsigned short B[2][2048];   // [2 mat][32 col][32 k]
    int tid = threadIdx.x, wid = tid >> 6, lane = tid & 63;
    int q = lane >> 4, nl = lane & 15;
    const unsigned short* abase = xgI + (size_t)pb * (64 * 4096);
    const unsigned short* bbase = wguI + ((size_t)((e * 32 + n) * 64)) * 2048;

    f32x4 accG[2][2], accU[2][2];
#pragma unroll
    for (int ms = 0; ms < 2; ++ms)
#pragma unroll
        for (int ns = 0; ns < 2; ++ns) {
            accG[ms][ns] = (f32x4){0.f, 0.f, 0.f, 0.f};
            accU[ms][ns] = (f32x4){0.f, 0.f, 0.f, 0.f};
        }

    auto STAGE = [&](int buf, int ks) {
        const unsigned short* at = abase + (size_t)ks * 4096;
        const unsigned short* bt = bbase + (size_t)ks * 2048;
        gld16(at + (wid * 2) * 512 + lane * 8, &A[buf][(wid * 2) * 512]);
        gld16(at + (wid * 2 + 1) * 512 + lane * 8, &A[buf][(wid * 2 + 1) * 512]);
        gld16(bt + wid * 512 + lane * 8, &B[buf][wid * 512]);
    };
    auto COMP = [&](int buf) {
        short8 af[2];
#pragma unroll
        for (int ms = 0; ms < 2; ++ms)
            af[ms] = *(const short8*)&A[buf][(wid * 32 + ms * 16 + nl) * 32 + q * 8];
#pragma unroll
        for (int ns = 0; ns < 2; ++ns) {
            int col = ns * 16 + nl;
            short8 bg = *(const short8*)&B[buf][col * 32 + q * 8];
            short8 bu = *(const short8*)&B[buf][1024 + col * 32 + q * 8];
#pragma unroll
            for (int ms = 0; ms < 2; ++ms) {
                accG[ms][ns] = __builtin_amdgcn_mfma_f32_16x16x32_bf16(af[ms], bg, accG[ms][ns], 0, 0, 0);
                accU[ms][ns] = __builtin_amdgcn_mfma_f32_16x16x32_bf16(af[ms], bu, accU[ms][ns], 0, 0, 0);
            }
        }
    };

    STAGE(0, 0);
    __syncthreads();
    for (int t = 0; t < 64; ++t) {
        if (t < 63) STAGE((t & 1) ^ 1, t + 1);
        COMP(t & 1);
        __syncthreads();
    }

    // epilogue: silu(g)*u -> h-image [pb][ksF(32)][128][32]; f = n*32 + ns*16 + nl
#pragma unroll
    for (int ms = 0; ms < 2; ++ms)
#pragma unroll
        for (int j = 0; j < 4; ++j) {
            int r = wid * 32 + ms * 16 + q * 4 + j;
#pragma unroll
            for (int ns = 0; ns < 2; ++ns) {
                float g = accG[ms][ns][j];
                float u = accU[ms][ns][j];
                float hv = (g / (1.f + __expf(-g))) * u;
                hI[((size_t)(pb * 32 + n)) * 4096 + r * 32 + ns * 16 + nl] = bf16bits(hv);
            }
        }
}

// ================= down GEMM: images + global_load_lds + weighted atomics =================
// tile 128(rows) x 64(D-cols), BK=32, 4 waves 2x2 (each 64x32). LDS 24KB.
__global__ __launch_bounds__(256, 6) void k_downI(const unsigned short* __restrict__ hI,
                                                  const unsigned short* __restrict__ wdI,
                                                  const int* __restrict__ offsets,
                                                  const int* __restrict__ pbe,
                                                  const int* __restrict__ pbm,
                                                  const int* __restrict__ npbp,
                                                  const int* __restrict__ token_ids,
                                                  const float* __restrict__ slot_w,
                                                  float* __restrict__ y) {
    int pb = blockIdx.y;
    if (pb >= npbp[0]) return;
    int n = blockIdx.x;                        // 0..31 (64-col block of D)
    int e = pbe[pb];
    int off = offsets[e];
    int ne = offsets[e + 1] - off;
    __shared__ __align__(16) unsigned short A[2][4096];   // [128][32]
    __shared__ __align__(16) unsigned short B[2][2048];   // [64 col][32 k]
    int tid = threadIdx.x, wid = tid >> 6, lane = tid & 63;
    int q = lane >> 4, nl = lane & 15;
    int wr = wid >> 1, wc = wid & 1;
    const unsigned short* abase = hI + (size_t)pb * (32 * 4096);
    const unsigned short* bbase = wdI + ((size_t)((e * 32 + n) * 32)) * 2048;

    f32x4 acc[4][2];
#pragma unroll
    for (int ms = 0; ms < 4; ++ms)
#pragma unroll
        for (int ns = 0; ns < 2; ++ns) acc[ms][ns] = (f32x4){0.f, 0.f, 0.f, 0.f};

    auto STAGE = [&](int buf, int ks) {
        const unsigned short* at = abase + (size_t)ks * 4096;
        const unsigned short* bt = bbase + (size_t)ks * 2048;
        gld16(at + (wid * 2) * 512 + lane * 8, &A[buf][(wid * 2) * 512]);
        gld16(at + (wid * 2 + 1) * 512 + lane * 8, &A[buf][(wid * 2 + 1) * 512]);
        gld16(bt + wid * 512 + lane * 8, &B[buf][wid * 512]);
    };
    auto COMP = [&](int buf) {
        short8 af[4];
#pragma unroll
        for (int ms = 0; ms < 4; ++ms)
            af[ms] = *(const short8*)&A[buf][(wr * 64 + ms * 16 + nl) * 32 + q * 8];
#pragma unroll
        for (int ns = 0; ns < 2; ++ns) {
            int col = wc * 32 + ns * 16 + nl;
            short8 bd = *(const short8*)&B[buf][col * 32 + q * 8];
#pragma unroll
            for (int ms = 0; ms < 4; ++ms)
                acc[ms][ns] = __builtin_amdgcn_mfma_f32_16x16x32_bf16(af[ms], bd, acc[ms][ns], 0, 0, 0);
        }
    };

    STAGE(0, 0);
    __syncthreads();
    for (int t = 0; t < 32; ++t) {
        if (t < 31) STAGE((t & 1) ^ 1, t + 1);
        COMP(t & 1);
        __syncthreads();
    }

#pragma unroll
    for (int ms = 0; ms < 4; ++ms)
#pragma unroll
        for (int j = 0; j < 4; ++j) {
            int r = wr * 64 + ms * 16 + q * 4 + j;
            int local = pbm[pb] * 128 + r;
            if (local < ne) {
                float w2 = slot_w[off + local];
                int tok = token_ids[off + local];
#pragma unroll
                for (int ns = 0; ns < 2; ++ns)
                    atomicAdd(&y[(size_t)tok * D_DIM + n * 64 + wc * 32 + ns * 16 + nl], acc[ms][ns][j] * w2);
            }
        }
}

// ===================== FALLBACK PATH (R11, proven) — used if ws too small =====================
__global__ __launch_bounds__(256) void k_gather_fb(const float* __restrict__ x,
                                                   const int* __restrict__ token_ids,
                                                   __hip_bfloat16* __restrict__ xg) {
    int s = blockIdx.x;
    const float* src = x + (size_t)token_ids[s] * D_DIM + threadIdx.x * 8;
    f32x4 a = *(const f32x4*)src;
    f32x4 b = *(const f32x4*)(src + 4);
    union { short8 v; unsigned u[4]; } w;
    w.u[0] = pk2bf(a.x, a.y); w.u[1] = pk2bf(a.z, a.w);
    w.u[2] = pk2bf(b.x, b.y); w.u[3] = pk2bf(b.z, b.w);
    *(short8*)((unsigned short*)xg + (size_t)s * D_DIM + threadIdx.x * 8) = w.v;
}

__global__ __launch_bounds__(256, 4) void k_gateup_fb(const __hip_bfloat16* __restrict__ xg,
                                                      const float* __restrict__ wg_all,
                                                      const float* __restrict__ wu_all,
                                                      const int* __restrict__ offsets,
                                                      __hip_bfloat16* __restrict__ hbuf) {
    unsigned b0 = blockIdx.x;
    unsigned w = (b0 & 7) * 1024u + (b0 >> 3);
    int mi = w & 31;
    int ni = (w >> 5) & 15;
    int e  = w >> 9;
    int off = offsets[e];
    int n_e = offsets[e + 1] - off;
    int m0 = mi * 64;
    if (m0 >= n_e) return;
    int n0 = ni * 64;
    const float* wg = wg_all + (size_t)e * (D_DIM * F_DIM);
    const float* wu = wu_all + (size_t)e * (D_DIM * F_DIM);
    __shared__ unsigned short As[2][64 * 40];
    __shared__ unsigned short Bs[2][2][64 * 40];
    int tid = threadIdx.x;
    int wid = tid >> 6, lane = tid & 63;
    int q = lane >> 4, nl = lane & 15;
    int wr = wid >> 1, wc = wid & 1;
    int arow = tid >> 2, acg = (tid & 3) * 8;
    int sg = off + m0 + arow; if (sg > NSLOT - 1) sg = NSLOT - 1;
    const unsigned short* xrow = (const unsigned short*)xg + (size_t)sg * D_DIM;
    int bkr = (tid >> 4) * 2;
    int bcol = (tid & 15) * 4;
    short8 rA;
    f32x4 rg[2], ru[2];
    f32x4 accG[2][2], accU[2][2];
#pragma unroll
    for (int ms = 0; ms < 2; ++ms)
#pragma unroll
        for (int ns = 0; ns < 2; ++ns) {
            accG[ms][ns] = (f32x4){0.f, 0.f, 0.f, 0.f};
            accU[ms][ns] = (f32x4){0.f, 0.f, 0.f, 0.f};
        }
    auto loadG = [&](int k0) {
        rA = *(const short8*)(xrow + k0 + acg);
        size_t o0 = (size_t)(k0 + bkr) * F_DIM + n0 + bcol;
        rg[0] = *(const f32x4*)(wg + o0);
        rg[1] = *(const f32x4*)(wg + o0 + F_DIM);
        ru[0] = *(const f32x4*)(wu + o0);
        ru[1] = *(const f32x4*)(wu + o0 + F_DIM);
    };
    auto writeL = [&](int b) {
        *(short8*)&As[b][arow * 40 + acg] = rA;
#pragma unroll
        for (int j = 0; j < 4; ++j) {
            int col = bcol + j;
            int kk = bkr ^ (((col >> 3) & 3) << 3);
            *(unsigned*)&Bs[b][0][col * 40 + kk] = pk2bf(rg[0][j], rg[1][j]);
            *(unsigned*)&Bs[b][1][col * 40 + kk] = pk2bf(ru[0][j], ru[1][j]);
        }
    };
    auto compute = [&](int b) {
        short8 af[2];
#pragma unroll
        for (int ms = 0; ms < 2; ++ms)
            af[ms] = *(const short8*)&As[b][(wr * 32 + ms * 16 + nl) * 40 + q * 8];
#pragma unroll
        for (int ns = 0; ns < 2; ++ns) {
            int col = wc * 32 + ns * 16 + nl;
            int colb = col * 40 + 8 * (q ^ ((col >> 3) & 3));
            short8 bg = *(const short8*)&Bs[b][0][colb];
            short8 bu = *(const short8*)&Bs[b][1][colb];
#pragma unroll
            for (int ms = 0; ms < 2; ++ms) {
                accG[ms][ns] = __builtin_amdgcn_mfma_f32_16x16x32_bf16(af[ms], bg, accG[ms][ns], 0, 0, 0);
                accU[ms][ns] = __builtin_amdgcn_mfma_f32_16x16x32_bf16(af[ms], bu, accU[ms][ns], 0, 0, 0);
            }
        }
    };
    loadG(0); writeL(0);
    __syncthreads();
    for (int t = 0; t < D_DIM / 32; ++t) {
        int b = t & 1;
        if (t < D_DIM / 32 - 1) loadG((t + 1) * 32);
        compute(b);
        if (t < D_DIM / 32 - 1) writeL(b ^ 1);
        __syncthreads();
    }
#pragma unroll
    for (int ms = 0; ms < 2; ++ms)
#pragma unroll
        for (int j = 0; j < 4; ++j) {
            int g2 = m0 + wr * 32 + ms * 16 + q * 4 + j;
            if (g2 < n_e) {
                size_t hbase = (size_t)(off + g2) * F_DIM;
#pragma unroll
                for (int ns = 0; ns < 2; ++ns) {
                    float g = accG[ms][ns][j];
                    float u = accU[ms][ns][j];
                    float hv = (g / (1.f + __expf(-g))) * u;
                    hbuf[hbase + n0 + wc * 32 + ns * 16 + nl] = __float2bfloat16(hv);
                }
            }
        }
}

__global__ __launch_bounds__(256, 4) void k_down_fb(const __hip_bfloat16* __restrict__ hbuf,
                                                    const float* __restrict__ wd_all,
                                                    const int* __restrict__ offsets,
                                                    const int* __restrict__ token_ids,
                                                    const float* __restrict__ slot_w,
                                                    float* __restrict__ y) {
    unsigned b0 = blockIdx.x;
    unsigned w = (b0 & 7) * 2048u + (b0 >> 3);
    int mi = w & 31;
    int ni = (w >> 5) & 31;
    int e  = w >> 10;
    int off = offsets[e];
    int n_e = offsets[e + 1] - off;
    int m0 = mi * 64;
    if (m0 >= n_e) return;
    int n0 = ni * 64;
    const float* wd = wd_all + (size_t)e * (F_DIM * D_DIM);
    __shared__ unsigned short As[2][64 * 40];
    __shared__ unsigned short Bs[2][64 * 40];
    int tid = threadIdx.x;
    int wid = tid >> 6, lane = tid & 63;
    int q = lane >> 4, nl = lane & 15;
    int wr = wid >> 1, wc = wid & 1;
    int arow = tid >> 2, acg = (tid & 3) * 8;
    int sg = off + m0 + arow; if (sg > NSLOT - 1) sg = NSLOT - 1;
    const unsigned short* hrow = (const unsigned short*)hbuf + (size_t)sg * F_DIM;
    int bkr = (tid >> 4) * 2;
    int bcol = (tid & 15) * 4;
    short8 rh;
    f32x4 rd[2];
    f32x4 acc[2][2];
#pragma unroll
    for (int ms = 0; ms < 2; ++ms)
#pragma unroll
        for (int ns = 0; ns < 2; ++ns) acc[ms][ns] = (f32x4){0.f, 0.f, 0.f, 0.f};
    auto loadG = [&](int k0) {
        rh = *(const short8*)(hrow + k0 + acg);
        size_t o0 = (size_t)(k0 + bkr) * D_DIM + n0 + bcol;
        rd[0] = *(const f32x4*)(wd + o0);
        rd[1] = *(const f32x4*)(wd + o0 + D_DIM);
    };
    auto writeL = [&](int b) {
        *(short8*)&As[b][arow * 40 + acg] = rh;
#pragma unroll
        for (int j = 0; j < 4; ++j) {
            int col = bcol + j;
            int kk = bkr ^ (((col >> 3) & 3) << 3);
            *(unsigned*)&Bs[b][col * 40 + kk] = pk2bf(rd[0][j], rd[1][j]);
        }
    };
    auto compute = [&](int b) {
        short8 af[2];
#pragma unroll
        for (int ms = 0; ms < 2; ++ms)
            af[ms] = *(const short8*)&As[b][(wr * 32 + ms * 16 + nl) * 40 + q * 8];
#pragma unroll
        for (int ns = 0; ns < 2; ++ns) {
            int col = wc * 32 + ns * 16 + nl;
            short8 bd = *(const short8*)&Bs[b][col * 40 + 8 * (q ^ ((col >> 3) & 3))];
#pragma unroll
            for (int ms = 0; ms < 2; ++ms)
                acc[ms][ns] = __builtin_amdgcn_mfma_f32_16x16x32_bf16(af[ms], bd, acc[ms][ns], 0, 0, 0);
        }
    };
    loadG(0); writeL(0);
    __syncthreads();
    for (int t = 0; t < F_DIM / 32; ++t) {
        int b = t & 1;
        if (t < F_DIM / 32 - 1) loadG((t + 1) * 32);
        compute(b);
        if (t < F_DIM / 32 - 1) writeL(b ^ 1);
        __syncthreads();
    }
#pragma unroll
    for (int ms = 0; ms < 2; ++ms)
#pragma unroll
        for (int j = 0; j < 4; ++j) {
            int g2 = m0 + wr * 32 + ms * 16 + q * 4 + j;
            if (g2 < n_e) {
                float w2 = slot_w[off + g2];
                int t = token_ids[off + g2];
#pragma unroll
                for (int ns = 0; ns < 2; ++ns)
                    atomicAdd(&y[(size_t)t * D_DIM + n0 + wc * 32 + ns * 16 + nl], acc[ms][ns][j] * w2);
            }
        }
}

extern "C" void kernel_launch(void* const* d_in, const int* in_sizes, int n_in,
                              void* d_out, int out_size, void* d_ws, size_t ws_size,
                              hipStream_t stream) {
    const float* x      = (const float*)d_in[0];
    const float* w_gate = (const float*)d_in[1];
    const float* w_g    = (const float*)d_in[2];
    const float* w_u    = (const float*)d_in[3];
    const float* w_d    = (const float*)d_in[4];
    const float* bias   = (const float*)d_in[5];
    float* y = (float*)d_out;

    char* ws = (char*)d_ws;
    int*   counts    = (int*)(ws + 0);
    int*   offsets   = (int*)(ws + 64);
    int*   cursors   = (int*)(ws + 192);
    int*   pbe       = (int*)(ws + 256);
    int*   pbm       = (int*)(ws + 512);
    int*   npbp      = (int*)(ws + 768);
    int*   topk_idx  = (int*)(ws + 1024);
    float* topk_w    = (float*)(ws + 17408);
    int*   token_ids = (int*)(ws + 33792);
    float* slot_w    = (float*)(ws + 50176);

    const size_t IMG0 = 66560;
    unsigned short* xgI  = (unsigned short*)(ws + IMG0);                      // 25165824
    unsigned short* hI   = (unsigned short*)(ws + IMG0 + 25165824);           // 12582912
    unsigned short* wguI = (unsigned short*)(ws + IMG0 + 37748736);           // 134217728
    unsigned short* wdI  = (unsigned short*)(ws + IMG0 + 171966464);          // 67108864
    const size_t NEED = IMG0 + 171966464 + 67108864;                          // ~239.1 MB

    hipMemsetAsync(ws, 0, 1024, stream);
    hipMemsetAsync(d_out, 0, (size_t)out_size * sizeof(float), stream);

    k_route<<<T_TOK, 64, 0, stream>>>(x, w_gate, bias, topk_idx, topk_w, counts);
    k_offsets<<<1, 64, 0, stream>>>(counts, offsets, cursors, pbe, pbm, npbp);
    k_scatter<<<(NSLOT + 255) / 256, 256, 0, stream>>>(topk_idx, topk_w, cursors, token_ids, slot_w);

    if (ws_size >= NEED) {
        k_gatherI<<<dim3(64, 48), 256, 0, stream>>>(x, token_ids, offsets, pbe, pbm, npbp, xgI);
        k_prep_gu<<<dim3(64, 32, 16), 256, 0, stream>>>(w_g, w_u, wguI);
        k_prep_d<<<dim3(32, 32, 16), 256, 0, stream>>>(w_d, wdI);
        k_gateupI<<<dim3(32, 48), 256, 0, stream>>>(xgI, wguI, pbe, npbp, hI);
        k_downI<<<dim3(32, 48), 256, 0, stream>>>(hI, wdI, offsets, pbe, pbm, npbp, token_ids, slot_w, y);
    } else {
        __hip_bfloat16* hbuf = (__hip_bfloat16*)(ws + IMG0);                  // 8.39 MB
        __hip_bfloat16* xg   = (__hip_bfloat16*)(ws + IMG0 + 8388608);        // 16.8 MB
        k_gather_fb<<<NSLOT, 256, 0, stream>>>(x, token_ids, xg);
        k_gateup_fb<<<16 * 32 * E_NUM, 256, 0, stream>>>(xg, w_g, w_u, offsets, hbuf);
        k_down_fb<<<32 * 32 * E_NUM, 256, 0, stream>>>(hbuf, w_d, offsets, token_ids, slot_w, y);
    }
}